// Round 4
// baseline (329.640 us; speedup 1.0000x reference)
//
#include <hip/hip_runtime.h>

// Bilinear warp (grid_sample, zeros padding) of frame_t (8,64,256,256) fp32
// by flow_field (8,2,256,256) fp32.
//   ix = px + 0.5*flow_x ; iy = py + 0.5*flow_y   (normalization collapses)
//
// R4 structure:
//  - block = (b, 16-row band, 8-channel group). Per-pixel weights + LDS tap
//    addresses precomputed ONCE into registers (R3 recomputed per channel ->
//    40% VALUBusy), reused across the 8-channel inner loop.
//  - window = 60 rows x stride 260 (16B-aligned float4 staging; bank =
//    (4y+x)&31 decorrelates rows). Guard col x=256 = dup of col 255; front
//    guard float at index -1 -> the (x0,x0+1) tap pair is correct at edges
//    with zero weights hitting finite (never uninitialized-NaN) data.
//  - taps fetched as 2x ds_read2_b32 (pairs) instead of 4x ds_read_b32.
//  - |disp|>21 escapes (possible max ~22.4 = 4*z_max) -> per-row wave-level
//    flag -> full global recompute fallback (execz-free when unused).
//  - blockIdx low 3 bits = b (XCD-local image); band fastest -> 44/60-row
//    window overlap between consecutive blocks stays in L2.

#define B_ 8
#define C_ 64
#define H_ 256
#define W_ 256
#define HW_ (H_ * W_)
#define BAND 16
#define NBAND (H_ / BAND)     // 16
#define CG 8
#define NCG (C_ / CG)         // 8
#define HALO 21
#define WROWS 60              // rows r0-21 .. r0+38
#define WSTRIDE 260           // keeps float4 staging 16B-aligned
#define WFLOATS (WROWS * WSTRIDE)   // 15600 floats; +1 guard = 62404 B

__global__ __launch_bounds__(256, 2) void warp_bilinear_kernel(
    const float* __restrict__ frame,   // (8,64,256,256)
    const float* __restrict__ flow,    // (8,2,256,256)
    float* __restrict__ out)           // (8,64,256,256)
{
    __shared__ float winbuf[WFLOATS + 1];
    float* win = winbuf + 1;           // win[-1] is legal (front guard)

    const int blk  = blockIdx.x;
    const int b    = blk & 7;          // XCD-local batch
    const int t    = blk >> 3;
    const int band = t & (NBAND - 1);  // fastest -> L2 window overlap
    const int cg   = t >> 4;

    const int r0  = band * BAND;
    const int wlo = r0 - HALO;
    const int tid = threadIdx.x;
    const int px  = tid;

    const float* __restrict__ flx = flow + (size_t)(b * 2 + 0) * HW_;
    const float* __restrict__ fly = flow + (size_t)(b * 2 + 1) * HW_;

    // ---- per-pixel gather data, computed once, reused for CG channels ----
    float w00[BAND], w01[BAND], w10[BAND], w11[BAND];
    int   A0[BAND], A1[BAND];
    unsigned wave_esc = 0u;

#pragma unroll
    for (int r = 0; r < BAND; ++r) {
        const int py = r0 + r;
        const int sp = py * W_ + px;
        const float fx = flx[sp];
        const float fy = fly[sp];
        const float ix = (float)px + 0.5f * fx;
        const float iy = (float)py + 0.5f * fy;
        const float ix0f = floorf(ix);
        const float iy0f = floorf(iy);
        const float tx = ix - ix0f;
        const float ty = iy - iy0f;
        const int ix0 = (int)ix0f;
        const int iy0 = (int)iy0f;
        const int ix1 = ix0 + 1;
        const int iy1 = iy0 + 1;
        const float vx0 = ((unsigned)ix0 < (unsigned)W_) ? 1.f : 0.f;
        const float vx1 = ((unsigned)ix1 < (unsigned)W_) ? 1.f : 0.f;
        const float vy0 = ((unsigned)iy0 < (unsigned)H_) ? 1.f : 0.f;
        const float vy1 = ((unsigned)iy1 < (unsigned)H_) ? 1.f : 0.f;
        w00[r] = (1.f - ty) * (1.f - tx) * vy0 * vx0;
        w01[r] = (1.f - ty) * tx         * vy0 * vx1;
        w10[r] = ty         * (1.f - tx) * vy1 * vx0;
        w11[r] = ty         * tx         * vy1 * vx1;
        const int yc0 = min(max(iy0, 0), H_ - 1);
        const int yc1 = min(max(iy1, 0), H_ - 1);
        const int bx  = min(max(ix0, -1), W_ - 1);   // pair base (x0, x0+1)
        int wr0 = yc0 - wlo;
        int wr1 = yc1 - wlo;
        const bool esc = ((unsigned)wr0 >= (unsigned)WROWS) ||
                         ((unsigned)wr1 >= (unsigned)WROWS);
        wr0 = min(max(wr0, 0), WROWS - 1);
        wr1 = min(max(wr1, 0), WROWS - 1);
        A0[r] = wr0 * WSTRIDE + bx;
        A1[r] = wr1 * WSTRIDE + bx;
        if (__any(esc)) wave_esc |= (1u << r);
    }

    if (tid == 0) winbuf[0] = 0.f;     // front guard: finite

    const size_t cbase = ((size_t)b * C_ + (size_t)cg * CG) * HW_;
    const float* __restrict__ src0 = frame + cbase;
    float* __restrict__ dst0 = out + cbase;

    for (int cc = 0; cc < CG; ++cc) {
        const float* __restrict__ src = src0 + (size_t)cc * HW_;
        float* __restrict__ dst = dst0 + (size_t)cc * HW_;

        // ---- stage 60-row window, coalesced float4, 16B-aligned LDS ----
#pragma unroll
        for (int it = 0; it < WROWS / 4; ++it) {       // 15 passes x 4 rows
            const int wr = it * 4 + (tid >> 6);
            const int x4 = (tid & 63) * 4;
            const int gy = min(max(wlo + wr, 0), H_ - 1);
            const float4 v = *(const float4*)(src + gy * W_ + x4);
            *(float4*)(win + wr * WSTRIDE + x4) = v;
        }
        if (tid < WROWS) {                             // guard col x=256
            const int gy = min(max(wlo + tid, 0), H_ - 1);
            win[tid * WSTRIDE + 256] = src[gy * W_ + 255];
        }
        __syncthreads();

        // ---- gather: 2x ds_read2_b32 + 4 FMA + nt store per output ----
#pragma unroll
        for (int r = 0; r < BAND; ++r) {
            float v = w00[r] * win[A0[r]]     + w01[r] * win[A0[r] + 1]
                    + w10[r] * win[A1[r]]     + w11[r] * win[A1[r] + 1];
            if (wave_esc & (1u << r)) {
                // rare: |disp| > HALO for some lane -> recompute from global
                const int py = r0 + r;
                const int sp = py * W_ + px;
                const float fx = flx[sp];
                const float fy = fly[sp];
                const float ix = (float)px + 0.5f * fx;
                const float iy = (float)py + 0.5f * fy;
                const float ix0f = floorf(ix);
                const float iy0f = floorf(iy);
                const float tx = ix - ix0f;
                const float ty = iy - iy0f;
                const int ix0 = (int)ix0f;
                const int iy0 = (int)iy0f;
                const int ix1 = ix0 + 1;
                const int iy1 = iy0 + 1;
                const float vx0 = ((unsigned)ix0 < (unsigned)W_) ? 1.f : 0.f;
                const float vx1 = ((unsigned)ix1 < (unsigned)W_) ? 1.f : 0.f;
                const float vy0 = ((unsigned)iy0 < (unsigned)H_) ? 1.f : 0.f;
                const float vy1 = ((unsigned)iy1 < (unsigned)H_) ? 1.f : 0.f;
                const int xc0 = min(max(ix0, 0), W_ - 1);
                const int xc1 = min(max(ix1, 0), W_ - 1);
                const int yc0 = min(max(iy0, 0), H_ - 1);
                const int yc1 = min(max(iy1, 0), H_ - 1);
                v = (1.f - ty) * (1.f - tx) * vy0 * vx0 * src[yc0 * W_ + xc0]
                  + (1.f - ty) * tx         * vy0 * vx1 * src[yc0 * W_ + xc1]
                  + ty         * (1.f - tx) * vy1 * vx0 * src[yc1 * W_ + xc0]
                  + ty         * tx         * vy1 * vx1 * src[yc1 * W_ + xc1];
            }
            __builtin_nontemporal_store(v, dst + (r0 + r) * W_ + px);
        }
        __syncthreads();   // protect window before next channel's staging
    }
}

extern "C" void kernel_launch(void* const* d_in, const int* in_sizes, int n_in,
                              void* d_out, int out_size, void* d_ws, size_t ws_size,
                              hipStream_t stream) {
    const float* frame = (const float*)d_in[0];
    const float* flow  = (const float*)d_in[1];
    float* out = (float*)d_out;

    dim3 grid(B_ * NBAND * NCG);   // 1024 blocks: (cg, band, b), b fastest
    dim3 block(256);
    warp_bilinear_kernel<<<grid, block, 0, stream>>>(frame, flow, out);
}